// Round 5
// baseline (1176.346 us; speedup 1.0000x reference)
//
#include <hip/hip_runtime.h>
#include <hip/hip_bf16.h>
#include <hip/hip_cooperative_groups.h>

namespace cg = cooperative_groups;

#define N_NODES 50000
#define N_EDGES 800000
#define DIM_IN  128
#define DIM_OUT 64
#define HEADS   4
#define NEG_SLOPE 0.2f
#define NPB 32                                    // nodes per gemm block
#define GEMM_BLOCKS ((N_NODES + NPB - 1) / NPB)   // 1563
#define N_PAD (GEMM_BLOCKS * NPB)                 // 50016
#define PAD 64                                    // padded CSR slots per node (deg ~Poisson(16); guarded)
#define CHUNKS 128                                // edge chunks
#define EPC (N_EDGES / CHUNKS)                    // 6250 edges per chunk
#define RANGES 128                                // src ranges (single-writer CSR build)
#define RSPAN 391                                 // 128*391 = 50048 >= N_NODES
#define HTOT (RANGES * CHUNKS)                    // 16384 histogram entries
#define XROW 136                                  // LDS row stride (shorts) for x hi/lo
#define LTROW 260                                 // LDS row stride (shorts) for transpose buffer
#define FUSED_GROUPS ((N_NODES + 3) / 4)          // 12500 groups of 4 nodes (1/wave)
#define SMEM_BYTES (2 * NPB * XROW * 2)           // 17408

typedef __attribute__((ext_vector_type(8))) short short8;
typedef __attribute__((ext_vector_type(4))) short short4v;
typedef __attribute__((ext_vector_type(4))) float f32x4;

// bf16 helpers (RNE pack, exact shift unpack)
__device__ __forceinline__ unsigned int f2bf(float f) {
    unsigned int u = __float_as_uint(f);
    return (u + 0x7FFFu + ((u >> 16) & 1u)) >> 16;
}
__device__ __forceinline__ float bf2f(unsigned int b) {
    return __uint_as_float(b << 16);
}

// ================= role bodies (shared by mega kernel and fallback path) =========

// ---- pack W into MFMA B-frag hi/lo; i = fragment-lane 0..4095
__device__ __forceinline__ void packW_role(
    int i, const float* __restrict__ W,
    unsigned short* __restrict__ Wph, unsigned short* __restrict__ Wpl)
{
    const int lane = i & 63, nt = (i >> 6) & 3, kc = (i >> 8) & 3, h = (i >> 10) & 3;
    const int col = lane & 15, quad = lane >> 4;
    unsigned short hv[8], lv[8];
#pragma unroll
    for (int j = 0; j < 8; ++j) {
        const int k = kc * 32 + quad * 8 + j;
        const int n = nt * 16 + col;
        const float f = W[h * (DIM_IN * DIM_OUT) + k * DIM_OUT + n];
        const unsigned int hb = f2bf(f);
        hv[j] = (unsigned short)hb;
        lv[j] = (unsigned short)f2bf(f - bf2f(hb));
    }
    *(short8*)(Wph + (size_t)i * 8) = *(short8*)hv;
    *(short8*)(Wpl + (size_t)i * 8) = *(short8*)lv;
}

// ---- per-chunk range histogram (256 threads); per-wave sub-hist kills contention
__device__ __forceinline__ void hist_role(
    int c, int t, const int* __restrict__ ei, unsigned int* __restrict__ histT,
    void* smemv)
{
    unsigned int (*h4)[RANGES] = (unsigned int (*)[RANGES])smemv;   // 2 KB
    const int w = t >> 6;
    for (int i = t; i < 4 * RANGES; i += 256) ((unsigned int*)h4)[i] = 0u;
    __syncthreads();
    const int* srcp = ei + c * EPC;
    for (int e = t; e < EPC; e += 256) {
        const int s = srcp[e];
        atomicAdd(&h4[w][s / RSPAN], 1u);
    }
    __syncthreads();
    if (t < RANGES)
        histT[t * CHUNKS + c] = h4[0][t] + h4[1][t] + h4[2][t] + h4[3][t];
}

// ---- exclusive prefix over histT (16384, r-major) -> S (one 256-thread block)
__device__ __forceinline__ void scan_role(
    int t, const unsigned int* __restrict__ histT, unsigned int* __restrict__ S,
    void* smemv)
{
    unsigned int* part = (unsigned int*)smemv;
    const uint4* H4 = (const uint4*)histT;
    unsigned int sum = 0;
#pragma unroll
    for (int q = 0; q < 16; ++q) {
        const uint4 v = H4[t * 16 + q];
        sum += v.x + v.y + v.z + v.w;
    }
    part[t] = sum;
    __syncthreads();
    for (int off = 1; off < 256; off <<= 1) {
        const unsigned int v = (t >= off) ? part[t - off] : 0u;
        __syncthreads();
        part[t] += v;
        __syncthreads();
    }
    unsigned int run = part[t] - sum;            // exclusive base
    uint4* S4 = (uint4*)S;
#pragma unroll
    for (int q = 0; q < 16; ++q) {
        const uint4 v = H4[t * 16 + q];
        uint4 o;
        o.x = run; run += v.x;
        o.y = run; run += v.y;
        o.z = run; run += v.z;
        o.w = run; run += v.w;
        S4[t * 16 + q] = o;
    }
}

// ---- MFMA gemm tile for nodes [nb, nb+32) (256 threads, smem = 17408 B)
__device__ __forceinline__ void gemm_role(
    int nb, int t, const float* __restrict__ x,
    const unsigned short* __restrict__ Wph, const unsigned short* __restrict__ Wpl,
    const float* __restrict__ a, unsigned short* __restrict__ h2,
    float* __restrict__ s_i, float* __restrict__ s_j, void* smemv)
{
    short* xh = (short*)smemv;            // [NPB][XROW]
    short* xl = xh + NPB * XROW;

    // stage x tile as hi/lo bf16 (32 nodes x 128 dims)
    {
        const float4* xg = (const float4*)x;
        const int base = nb * (DIM_IN / 4);
        const int limit = N_NODES * (DIM_IN / 4);
#pragma unroll
        for (int r = 0; r < 4; ++r) {
            const int idx = t + 256 * r;              // 0..1023
            const int gi = base + idx;
            float4 v = {0.f, 0.f, 0.f, 0.f};
            if (gi < limit) v = xg[gi];
            const int node = idx >> 5;
            const int dg = (idx & 31) * 4;
            unsigned short hs[4], ls[4];
            const float fv[4] = {v.x, v.y, v.z, v.w};
#pragma unroll
            for (int c = 0; c < 4; ++c) {
                const unsigned int hb = f2bf(fv[c]);
                hs[c] = (unsigned short)hb;
                ls[c] = (unsigned short)f2bf(fv[c] - bf2f(hb));
            }
            *(short4v*)(xh + node * XROW + dg) = *(short4v*)hs;
            *(short4v*)(xl + node * XROW + dg) = *(short4v*)ls;
        }
    }
    __syncthreads();

    const int w = t >> 6;        // wave id == head
    const int lane = t & 63;
    const int col = lane & 15, quad = lane >> 4;

    f32x4 acc[2][4];
#pragma unroll
    for (int mt = 0; mt < 2; ++mt)
#pragma unroll
        for (int nt = 0; nt < 4; ++nt) acc[mt][nt] = (f32x4){0.f, 0.f, 0.f, 0.f};

    const short8* Bh = (const short8*)Wph;
    const short8* Bl = (const short8*)Wpl;
#pragma unroll
    for (int kc = 0; kc < 4; ++kc) {
        const short8 ah0 = *(const short8*)(xh + (0 * 16 + col) * XROW + kc * 32 + quad * 8);
        const short8 al0 = *(const short8*)(xl + (0 * 16 + col) * XROW + kc * 32 + quad * 8);
        const short8 ah1 = *(const short8*)(xh + (1 * 16 + col) * XROW + kc * 32 + quad * 8);
        const short8 al1 = *(const short8*)(xl + (1 * 16 + col) * XROW + kc * 32 + quad * 8);
#pragma unroll
        for (int nt = 0; nt < 4; ++nt) {
            const int fi = ((w * 4 + kc) * 4 + nt) * 64 + lane;
            const short8 bh = Bh[fi];
            const short8 bl = Bl[fi];
            acc[0][nt] = __builtin_amdgcn_mfma_f32_16x16x32_bf16(ah0, bh, acc[0][nt], 0, 0, 0);
            acc[0][nt] = __builtin_amdgcn_mfma_f32_16x16x32_bf16(al0, bh, acc[0][nt], 0, 0, 0);
            acc[0][nt] = __builtin_amdgcn_mfma_f32_16x16x32_bf16(ah0, bl, acc[0][nt], 0, 0, 0);
            acc[1][nt] = __builtin_amdgcn_mfma_f32_16x16x32_bf16(ah1, bh, acc[1][nt], 0, 0, 0);
            acc[1][nt] = __builtin_amdgcn_mfma_f32_16x16x32_bf16(al1, bh, acc[1][nt], 0, 0, 0);
            acc[1][nt] = __builtin_amdgcn_mfma_f32_16x16x32_bf16(ah1, bl, acc[1][nt], 0, 0, 0);
        }
    }

    // scores: lane holds h[node=mt*16+quad*4+r][head=w][o=nt*16+col]
    float aiv[4], ajv[4];
#pragma unroll
    for (int nt = 0; nt < 4; ++nt) {
        aiv[nt] = a[w * (2 * DIM_OUT) + nt * 16 + col];
        ajv[nt] = a[w * (2 * DIM_OUT) + DIM_OUT + nt * 16 + col];
    }
#pragma unroll
    for (int mt = 0; mt < 2; ++mt) {
#pragma unroll
        for (int r = 0; r < 4; ++r) {
            float pi = 0.f, pj = 0.f;
#pragma unroll
            for (int nt = 0; nt < 4; ++nt) {
                pi = fmaf(acc[mt][nt][r], aiv[nt], pi);
                pj = fmaf(acc[mt][nt][r], ajv[nt], pj);
            }
#pragma unroll
            for (int off = 8; off > 0; off >>= 1) {
                pi += __shfl_down(pi, off, 16);
                pj += __shfl_down(pj, off, 16);
            }
            if (col == 0) {
                const int n = nb + mt * 16 + quad * 4 + r;
                s_i[n * HEADS + w] = pi;
                s_j[n * HEADS + w] = pj;
            }
        }
    }
    __syncthreads();   // xh/xl consumed; smem becomes the transpose buffer

    // stage transposed bf16 tile: lt[node][o*4+head] with padded row stride
    short* lt = (short*)smemv;
#pragma unroll
    for (int mt = 0; mt < 2; ++mt)
#pragma unroll
        for (int nt = 0; nt < 4; ++nt)
#pragma unroll
            for (int r = 0; r < 4; ++r)
                lt[(mt * 16 + quad * 4 + r) * LTROW + (nt * 16 + col) * 4 + w] =
                    (short)f2bf(acc[mt][nt][r]);
    __syncthreads();

    // dense write-out: 2048 uint2 = 16 KB, coalesced 8B stores
    uint2* hg = (uint2*)(h2 + (size_t)nb * (DIM_OUT * HEADS));
#pragma unroll
    for (int r = 0; r < 8; ++r) {
        const int idx = t + 256 * r;       // 0..2047
        const int node = idx >> 6;
        const int wo = idx & 63;
        hg[idx] = *(const uint2*)(lt + node * LTROW + wo * 4);
    }
    __syncthreads();   // lt consumed; safe to re-stage on next job iteration
}

// ---- bucket-scatter chunk c into range-contiguous ebuf runs
__device__ __forceinline__ void bucket_role(
    int c, int t, int NT, const int* __restrict__ ei,
    const unsigned int* __restrict__ S, unsigned int* __restrict__ ebuf,
    void* smemv)
{
    unsigned int* cur = (unsigned int*)smemv;    // [RANGES]
    if (t < RANGES) cur[t] = S[t * CHUNKS + c];
    __syncthreads();
    const int* srcp = ei + c * EPC;
    const int* dstp = ei + N_EDGES + c * EPC;
    for (int e = t; e < EPC; e += NT) {
        const int s = srcp[e];
        const int d = dstp[e];
        const int r = s / RSPAN;
        const unsigned int pos = atomicAdd(&cur[r], 1u);
        ebuf[pos] = ((unsigned int)(s - r * RSPAN) << 16) | (unsigned int)d;
    }
}

// ---- CSR build: block r is the ONLY writer of range r; emits cursor degrees
__device__ __forceinline__ void csr_role(
    int r, int t, int NT, const unsigned int* __restrict__ ebuf,
    const unsigned int* __restrict__ S, unsigned short* __restrict__ sdst,
    int* __restrict__ cursor, void* smemv)
{
    unsigned int* cur = (unsigned int*)smemv;    // [RSPAN]
    const unsigned int j0 = S[r * CHUNKS];
    const unsigned int j1 = (r + 1 < RANGES) ? S[(r + 1) * CHUNKS] : N_EDGES;
    for (int i = t; i < RSPAN; i += NT) cur[i] = 0u;
    __syncthreads();
    for (unsigned int e = j0 + t; e < j1; e += NT) {
        const unsigned int v = ebuf[e];
        const unsigned int sl = v >> 16;
        const unsigned int d = v & 0xFFFFu;
        const unsigned int slot = atomicAdd(&cur[sl], 1u);
        if (slot < PAD) sdst[(size_t)(r * RSPAN + sl) * PAD + slot] = (unsigned short)d;
    }
    __syncthreads();
    for (int i = t; i < RSPAN; i += NT) {
        const int n = r * RSPAN + i;
        if (n < N_NODES) cursor[n] = (int)cur[i];
    }
}

// ---- fused per-src softmax + aggregate, one wave per node (proven 62.6 us body)
__device__ __forceinline__ void fused_role(
    int n, int lane, const int* __restrict__ cursor,
    const unsigned short* __restrict__ sdst, const float* __restrict__ s_i,
    const float* __restrict__ s_j, const unsigned short* __restrict__ h2,
    float* __restrict__ out, float4* att_row, int* dst_row)
{
    const int d = min(cursor[n], PAD);
    const int start = n * PAD;

    float acc = 0.f;
    if (d > 0) {
        const float4 si = *(const float4*)(s_i + n * HEADS);
        float4 m4 = {-INFINITY, -INFINITY, -INFINITY, -INFINITY};
        float4 cz = {-INFINITY, -INFINITY, -INFINITY, -INFINITY};
        int cdst = 0;
        if (lane < d) {
            cdst = (int)sdst[start + lane];
            const float4 sj = *(const float4*)(s_j + cdst * HEADS);
            float z0 = si.x + sj.x, z1 = si.y + sj.y, z2 = si.z + sj.z, z3 = si.w + sj.w;
            cz.x = z0 >= 0.f ? z0 : NEG_SLOPE * z0;
            cz.y = z1 >= 0.f ? z1 : NEG_SLOPE * z1;
            cz.z = z2 >= 0.f ? z2 : NEG_SLOPE * z2;
            cz.w = z3 >= 0.f ? z3 : NEG_SLOPE * z3;
            m4 = cz;
        }
#pragma unroll
        for (int off = 32; off > 0; off >>= 1) {
            m4.x = fmaxf(m4.x, __shfl_xor(m4.x, off, 64));
            m4.y = fmaxf(m4.y, __shfl_xor(m4.y, off, 64));
            m4.z = fmaxf(m4.z, __shfl_xor(m4.z, off, 64));
            m4.w = fmaxf(m4.w, __shfl_xor(m4.w, off, 64));
        }
        float4 ex = {0.f, 0.f, 0.f, 0.f};
        if (lane < d) {
            ex.x = __expf(cz.x - m4.x);
            ex.y = __expf(cz.y - m4.y);
            ex.z = __expf(cz.z - m4.z);
            ex.w = __expf(cz.w - m4.w);
        }
        float4 sm = ex;
#pragma unroll
        for (int off = 32; off > 0; off >>= 1) {
            sm.x += __shfl_xor(sm.x, off, 64);
            sm.y += __shfl_xor(sm.y, off, 64);
            sm.z += __shfl_xor(sm.z, off, 64);
            sm.w += __shfl_xor(sm.w, off, 64);
        }
        if (lane < d) {
            att_row[lane] = make_float4(ex.x / sm.x, ex.y / sm.y, ex.z / sm.z, ex.w / sm.w);
            dst_row[lane] = cdst;
        }

        const unsigned short* hbase = h2 + lane * HEADS;
        int e = 0;
        for (; e + 8 <= d; e += 8) {
            uint2 hv[8];
            float4 at[8];
#pragma unroll
            for (int q = 0; q < 8; ++q) {
                const int dd = dst_row[e + q];
                at[q] = att_row[e + q];
                hv[q] = *(const uint2*)(hbase + (size_t)dd * (DIM_OUT * HEADS));
            }
#pragma unroll
            for (int q = 0; q < 8; ++q) {
                acc += at[q].x * bf2f(hv[q].x & 0xFFFFu) + at[q].y * bf2f(hv[q].x >> 16)
                     + at[q].z * bf2f(hv[q].y & 0xFFFFu) + at[q].w * bf2f(hv[q].y >> 16);
            }
        }
        for (; e + 4 <= d; e += 4) {
            uint2 hv[4];
            float4 at[4];
#pragma unroll
            for (int q = 0; q < 4; ++q) {
                const int dd = dst_row[e + q];
                at[q] = att_row[e + q];
                hv[q] = *(const uint2*)(hbase + (size_t)dd * (DIM_OUT * HEADS));
            }
#pragma unroll
            for (int q = 0; q < 4; ++q) {
                acc += at[q].x * bf2f(hv[q].x & 0xFFFFu) + at[q].y * bf2f(hv[q].x >> 16)
                     + at[q].z * bf2f(hv[q].y & 0xFFFFu) + at[q].w * bf2f(hv[q].y >> 16);
            }
        }
        for (; e < d; ++e) {
            const int dd = dst_row[e];
            const float4 a4 = att_row[e];
            const uint2 hv = *(const uint2*)(hbase + (size_t)dd * (DIM_OUT * HEADS));
            acc += a4.x * bf2f(hv.x & 0xFFFFu) + a4.y * bf2f(hv.x >> 16)
                 + a4.z * bf2f(hv.y & 0xFFFFu) + a4.w * bf2f(hv.y >> 16);
        }
    }
    out[n * DIM_OUT + lane] = 0.25f * acc;
}

// ================= ONE cooperative kernel: all 5 phases, 4 grid syncs ============
__global__ __launch_bounds__(256, 8) void mega_kernel(
    const float* __restrict__ x, const int* __restrict__ ei,
    const float* __restrict__ W, const float* __restrict__ a,
    unsigned short* __restrict__ Wph, unsigned short* __restrict__ Wpl,
    unsigned short* __restrict__ h2, float* __restrict__ s_i, float* __restrict__ s_j,
    unsigned int* __restrict__ histT, unsigned int* __restrict__ S,
    unsigned int* __restrict__ ebuf, unsigned short* __restrict__ sdst,
    int* __restrict__ cursor, float* __restrict__ out)
{
    __shared__ __align__(16) unsigned char smem[SMEM_BYTES];   // 17408 B, all phases
    const int b = blockIdx.x;
    const int t = threadIdx.x;
    const int G = gridDim.x;
    cg::grid_group grid = cg::this_grid();

    // ---- P1: pack W (blocks 0-15) + range histograms (blocks 16..143)
    if (b < 16)                    packW_role(b * 256 + t, W, Wph, Wpl);
    else if (b < 16 + CHUNKS)      hist_role(b - 16, t, ei, histT, smem);
    grid.sync();

    // ---- P2: scan (block 0) || MFMA gemm (remaining blocks, job-strided)
    if (b == 0) {
        scan_role(t, histT, S, smem);
    } else {
        for (int job = b - 1; job < GEMM_BLOCKS; job += (G - 1))
            gemm_role(job * NPB, t, x, Wph, Wpl, a, h2, s_i, s_j, smem);
    }
    grid.sync();

    // ---- P3: bucket-scatter (blocks 0..127)
    if (b < CHUNKS) bucket_role(b, t, 256, ei, S, ebuf, smem);
    grid.sync();

    // ---- P4: single-writer CSR build (blocks 0..127)
    if (b < RANGES) csr_role(b, t, 256, ebuf, S, sdst, cursor, smem);
    grid.sync();

    // ---- P5: fused softmax + aggregate, grid-strided (one wave per node)
    float4* att = (float4*)smem;                       // [4][64] = 4 KB
    int* dstl = (int*)(smem + 4 * 64 * sizeof(float4)); // [4][64] = 1 KB
    const int w = t >> 6;
    const int lane = t & 63;
    for (int g = b; g < FUSED_GROUPS; g += G) {
        const int n = g * 4 + w;
        if (n < N_NODES)
            fused_role(n, lane, cursor, sdst, s_i, s_j, h2, out,
                       att + w * 64, dstl + w * 64);
    }
}

// ================= fallback path (proven R4 kernels, via the same roles) =========
__global__ __launch_bounds__(256) void pack_hist_kernel(
    const float* __restrict__ W, unsigned short* __restrict__ Wph,
    unsigned short* __restrict__ Wpl, const int* __restrict__ ei,
    unsigned int* __restrict__ histT)
{
    __shared__ __align__(16) unsigned char fsmem[4 * RANGES * 4];
    const int b = blockIdx.x, t = threadIdx.x;
    if (b < 16) packW_role(b * 256 + t, W, Wph, Wpl);
    else        hist_role(b - 16, t, ei, histT, fsmem);
}

__global__ __launch_bounds__(256) void scan_gemm_kernel(
    const float* __restrict__ x, const unsigned short* __restrict__ Wph,
    const unsigned short* __restrict__ Wpl, const float* __restrict__ a,
    unsigned short* __restrict__ h2, float* __restrict__ s_i, float* __restrict__ s_j,
    const unsigned int* __restrict__ histT, unsigned int* __restrict__ S)
{
    __shared__ __align__(16) unsigned char fsmem[SMEM_BYTES];
    const int b = blockIdx.x, t = threadIdx.x;
    if (b == 0) scan_role(t, histT, S, fsmem);
    else        gemm_role((b - 1) * NPB, t, x, Wph, Wpl, a, h2, s_i, s_j, fsmem);
}

__global__ __launch_bounds__(512) void bucket_kernel(
    const int* __restrict__ ei, const unsigned int* __restrict__ S,
    unsigned int* __restrict__ ebuf)
{
    __shared__ __align__(16) unsigned char fsmem[RANGES * 4];
    bucket_role(blockIdx.x, threadIdx.x, 512, ei, S, ebuf, fsmem);
}

__global__ __launch_bounds__(512) void csr_kernel(
    const unsigned int* __restrict__ ebuf, const unsigned int* __restrict__ S,
    unsigned short* __restrict__ sdst, int* __restrict__ cursor)
{
    __shared__ __align__(16) unsigned char fsmem[RSPAN * 4];
    csr_role(blockIdx.x, threadIdx.x, 512, ebuf, S, sdst, cursor, fsmem);
}

__global__ __launch_bounds__(256) void fused_kernel(
    const int* __restrict__ cursor, const unsigned short* __restrict__ sdst,
    const float* __restrict__ s_i, const float* __restrict__ s_j,
    const unsigned short* __restrict__ h2, float* __restrict__ out)
{
    __shared__ float4 att_s[4][64];
    __shared__ int    dst_s[4][64];
    const int w = (threadIdx.x >> 6) & 3;
    const int lane = threadIdx.x & 63;
    const int n = blockIdx.x * 4 + w;
    if (n >= N_NODES) return;
    fused_role(n, lane, cursor, sdst, s_i, s_j, h2, out, &att_s[w][0], &dst_s[w][0]);
}

extern "C" void kernel_launch(void* const* d_in, const int* in_sizes, int n_in,
                              void* d_out, int out_size, void* d_ws, size_t ws_size,
                              hipStream_t stream) {
    const float* x  = (const float*)d_in[0];
    const int*   ei = (const int*)d_in[1];
    const float* W  = (const float*)d_in[2];
    const float* a  = (const float*)d_in[3];
    float* out = (float*)d_out;

    char* ws = (char*)d_ws;
    size_t off = 0;
    auto alloc = [&](size_t bytes) { void* p = ws + off; off = (off + bytes + 511) & ~size_t(511); return p; };
    unsigned short* h2  = (unsigned short*)alloc(sizeof(unsigned short) * N_PAD * DIM_OUT * HEADS); // 25.6 MB
    float* s_i    = (float*)alloc(sizeof(float) * N_PAD * HEADS);
    float* s_j    = (float*)alloc(sizeof(float) * N_PAD * HEADS);
    int*   cursor = (int*)alloc(sizeof(int) * N_NODES);                         // 200 KB
    unsigned short* sdst = (unsigned short*)alloc(sizeof(unsigned short) * N_NODES * PAD); // 6.4 MB
    unsigned int* histT  = (unsigned int*)alloc(sizeof(unsigned int) * HTOT);   // 64 KB
    unsigned int* S      = (unsigned int*)alloc(sizeof(unsigned int) * HTOT);   // 64 KB
    unsigned int* ebuf   = (unsigned int*)alloc(sizeof(unsigned int) * N_EDGES);// 3.2 MB
    unsigned short* Wph  = (unsigned short*)alloc(sizeof(unsigned short) * HEADS * DIM_IN * DIM_OUT); // 64 KB
    unsigned short* Wpl  = (unsigned short*)alloc(sizeof(unsigned short) * HEADS * DIM_IN * DIM_OUT); // 64 KB

    void* args[] = { (void*)&x, (void*)&ei, (void*)&W, (void*)&a,
                     (void*)&Wph, (void*)&Wpl, (void*)&h2, (void*)&s_i, (void*)&s_j,
                     (void*)&histT, (void*)&S, (void*)&ebuf, (void*)&sdst,
                     (void*)&cursor, (void*)&out };

    // one cooperative dispatch: 2048 blocks (8/CU @ 64 VGPR, 17.4 KB LDS)
    hipError_t rc = hipLaunchCooperativeKernel((const void*)mega_kernel,
                                               dim3(2048), dim3(256), args, 0, stream);
    if (rc != hipSuccess) {
        (void)hipGetLastError();
        rc = hipLaunchCooperativeKernel((const void*)mega_kernel,
                                        dim3(1024), dim3(256), args, 0, stream);
    }
    if (rc != hipSuccess) {
        (void)hipGetLastError();
        // fallback: proven 5-dispatch path
        pack_hist_kernel<<<16 + CHUNKS, 256, 0, stream>>>(W, Wph, Wpl, ei, histT);
        scan_gemm_kernel<<<1 + GEMM_BLOCKS, 256, 0, stream>>>(x, Wph, Wpl, a, h2, s_i, s_j, histT, S);
        bucket_kernel<<<CHUNKS, 512, 0, stream>>>(ei, S, ebuf);
        csr_kernel<<<RANGES, 512, 0, stream>>>(ebuf, S, sdst, cursor);
        fused_kernel<<<FUSED_GROUPS, 256, 0, stream>>>(cursor, sdst, s_i, s_j, h2, out);
    }
}

// Round 6
// 169.839 us; speedup vs baseline: 6.9262x; 6.9262x over previous
//
#include <hip/hip_runtime.h>
#include <hip/hip_bf16.h>

#define N_NODES 50000
#define N_EDGES 800000
#define DIM_IN  128
#define DIM_OUT 64
#define HEADS   4
#define NEG_SLOPE 0.2f
#define NPB 32                                    // nodes per gemm block
#define GEMM_BLOCKS ((N_NODES + NPB - 1) / NPB)   // 1563
#define N_PAD (GEMM_BLOCKS * NPB)                 // 50016
#define PAD 64                                    // padded CSR slots per node (deg ~Poisson(16); guarded)
#define CHUNKS 128                                // edge chunks
#define EPC (N_EDGES / CHUNKS)                    // 6250 edges per chunk
#define RANGES 128                                // src ranges (single-writer CSR build)
#define RSPAN 391                                 // 128*391 = 50048 >= N_NODES
#define OPITCH 132                                // offT row pitch (129 used, padded)
#define XROW 136                                  // LDS row stride (shorts) for x hi/lo
#define LTROW 260                                 // LDS row stride (shorts) for transpose buffer
#define SMEM_BYTES (2 * NPB * XROW * 2)           // 17408

typedef __attribute__((ext_vector_type(8))) short short8;
typedef __attribute__((ext_vector_type(4))) short short4v;
typedef __attribute__((ext_vector_type(4))) float f32x4;

// bf16 helpers (RNE pack, exact shift unpack)
__device__ __forceinline__ unsigned int f2bf(float f) {
    unsigned int u = __float_as_uint(f);
    return (u + 0x7FFFu + ((u >> 16) & 1u)) >> 16;
}
__device__ __forceinline__ float bf2f(unsigned int b) {
    return __uint_as_float(b << 16);
}

// ---- pack W into MFMA B-frag hi/lo; i = fragment-lane 0..4095
__device__ __forceinline__ void packW_role(
    int i, const float* __restrict__ W,
    unsigned short* __restrict__ Wph, unsigned short* __restrict__ Wpl)
{
    const int lane = i & 63, nt = (i >> 6) & 3, kc = (i >> 8) & 3, h = (i >> 10) & 3;
    const int col = lane & 15, quad = lane >> 4;
    unsigned short hv[8], lv[8];
#pragma unroll
    for (int j = 0; j < 8; ++j) {
        const int k = kc * 32 + quad * 8 + j;
        const int n = nt * 16 + col;
        const float f = W[h * (DIM_IN * DIM_OUT) + k * DIM_OUT + n];
        const unsigned int hb = f2bf(f);
        hv[j] = (unsigned short)hb;
        lv[j] = (unsigned short)f2bf(f - bf2f(hb));
    }
    *(short8*)(Wph + (size_t)i * 8) = *(short8*)hv;
    *(short8*)(Wpl + (size_t)i * 8) = *(short8*)lv;
}

// ---------------- D1: pack W (blocks 0-7) + per-chunk local range-sort (8..135) ---
// Each chunk block: LDS histogram -> LDS exclusive scan -> chunk-local sorted ebuf
// + ABSOLUTE offsets offT[c][r]. No cross-block deps => no global scan dispatch.
__global__ __launch_bounds__(512) void sort_kernel(
    const float* __restrict__ W, unsigned short* __restrict__ Wph,
    unsigned short* __restrict__ Wpl, const int* __restrict__ ei,
    unsigned int* __restrict__ offT, unsigned int* __restrict__ ebuf)
{
    const int b = blockIdx.x;
    const int t = threadIdx.x;
    if (b < 8) { packW_role(b * 512 + t, W, Wph, Wpl); return; }

    __shared__ unsigned int hist[RANGES];
    __shared__ unsigned int scn[RANGES + 1];
    __shared__ unsigned int cur[RANGES];
    const int c = b - 8;
    if (t < RANGES) hist[t] = 0u;
    __syncthreads();
    const int* srcp = ei + c * EPC;
    const int* dstp = ei + N_EDGES + c * EPC;
    for (int e = t; e < EPC; e += 512) atomicAdd(&hist[srcp[e] / RSPAN], 1u);
    __syncthreads();
    // Hillis-Steele scan (threads 0..127), exclusive via scn[t+1]=hist[t]
    if (t < RANGES) scn[t + 1] = hist[t];
    if (t == 0) scn[0] = 0u;
    __syncthreads();
    for (int off = 1; off < RANGES; off <<= 1) {
        unsigned int v = 0u;
        if (t < RANGES && (t + 1) > off) v = scn[t + 1 - off];
        __syncthreads();
        if (t < RANGES) scn[t + 1] += v;
        __syncthreads();
    }
    if (t < RANGES) {
        cur[t] = scn[t];
        offT[c * OPITCH + t] = (unsigned int)(c * EPC) + scn[t];
    }
    if (t == 0) offT[c * OPITCH + RANGES] = (unsigned int)((c + 1) * EPC);
    __syncthreads();
    unsigned int* eb = ebuf + (size_t)c * EPC;
    for (int e = t; e < EPC; e += 512) {
        const int s = srcp[e];
        const int d = dstp[e];
        const int r = s / RSPAN;
        const unsigned int pos = atomicAdd(&cur[r], 1u);
        eb[pos] = ((unsigned int)(s - r * RSPAN) << 16) | (unsigned int)d;
    }
}

// ---- MFMA gemm tile for nodes [nb, nb+32) (256 threads, smem = 17408 B)
__device__ __forceinline__ void gemm_role(
    int nb, int t, const float* __restrict__ x,
    const unsigned short* __restrict__ Wph, const unsigned short* __restrict__ Wpl,
    const float* __restrict__ a, unsigned short* __restrict__ h2,
    float* __restrict__ s_i, float* __restrict__ s_j, void* smemv)
{
    short* xh = (short*)smemv;            // [NPB][XROW]
    short* xl = xh + NPB * XROW;

    // stage x tile as hi/lo bf16 (32 nodes x 128 dims)
    {
        const float4* xg = (const float4*)x;
        const int base = nb * (DIM_IN / 4);
        const int limit = N_NODES * (DIM_IN / 4);
#pragma unroll
        for (int r = 0; r < 4; ++r) {
            const int idx = t + 256 * r;              // 0..1023
            const int gi = base + idx;
            float4 v = {0.f, 0.f, 0.f, 0.f};
            if (gi < limit) v = xg[gi];
            const int node = idx >> 5;
            const int dg = (idx & 31) * 4;
            unsigned short hs[4], ls[4];
            const float fv[4] = {v.x, v.y, v.z, v.w};
#pragma unroll
            for (int c = 0; c < 4; ++c) {
                const unsigned int hb = f2bf(fv[c]);
                hs[c] = (unsigned short)hb;
                ls[c] = (unsigned short)f2bf(fv[c] - bf2f(hb));
            }
            *(short4v*)(xh + node * XROW + dg) = *(short4v*)hs;
            *(short4v*)(xl + node * XROW + dg) = *(short4v*)ls;
        }
    }
    __syncthreads();

    const int w = t >> 6;        // wave id == head
    const int lane = t & 63;
    const int col = lane & 15, quad = lane >> 4;

    f32x4 acc[2][4];
#pragma unroll
    for (int mt = 0; mt < 2; ++mt)
#pragma unroll
        for (int nt = 0; nt < 4; ++nt) acc[mt][nt] = (f32x4){0.f, 0.f, 0.f, 0.f};

    const short8* Bh = (const short8*)Wph;
    const short8* Bl = (const short8*)Wpl;
#pragma unroll
    for (int kc = 0; kc < 4; ++kc) {
        const short8 ah0 = *(const short8*)(xh + (0 * 16 + col) * XROW + kc * 32 + quad * 8);
        const short8 al0 = *(const short8*)(xl + (0 * 16 + col) * XROW + kc * 32 + quad * 8);
        const short8 ah1 = *(const short8*)(xh + (1 * 16 + col) * XROW + kc * 32 + quad * 8);
        const short8 al1 = *(const short8*)(xl + (1 * 16 + col) * XROW + kc * 32 + quad * 8);
#pragma unroll
        for (int nt = 0; nt < 4; ++nt) {
            const int fi = ((w * 4 + kc) * 4 + nt) * 64 + lane;
            const short8 bh = Bh[fi];
            const short8 bl = Bl[fi];
            acc[0][nt] = __builtin_amdgcn_mfma_f32_16x16x32_bf16(ah0, bh, acc[0][nt], 0, 0, 0);
            acc[0][nt] = __builtin_amdgcn_mfma_f32_16x16x32_bf16(al0, bh, acc[0][nt], 0, 0, 0);
            acc[0][nt] = __builtin_amdgcn_mfma_f32_16x16x32_bf16(ah0, bl, acc[0][nt], 0, 0, 0);
            acc[1][nt] = __builtin_amdgcn_mfma_f32_16x16x32_bf16(ah1, bh, acc[1][nt], 0, 0, 0);
            acc[1][nt] = __builtin_amdgcn_mfma_f32_16x16x32_bf16(al1, bh, acc[1][nt], 0, 0, 0);
            acc[1][nt] = __builtin_amdgcn_mfma_f32_16x16x32_bf16(ah1, bl, acc[1][nt], 0, 0, 0);
        }
    }

    // scores: lane holds h[node=mt*16+quad*4+r][head=w][o=nt*16+col]
    float aiv[4], ajv[4];
#pragma unroll
    for (int nt = 0; nt < 4; ++nt) {
        aiv[nt] = a[w * (2 * DIM_OUT) + nt * 16 + col];
        ajv[nt] = a[w * (2 * DIM_OUT) + DIM_OUT + nt * 16 + col];
    }
#pragma unroll
    for (int mt = 0; mt < 2; ++mt) {
#pragma unroll
        for (int r = 0; r < 4; ++r) {
            float pi = 0.f, pj = 0.f;
#pragma unroll
            for (int nt = 0; nt < 4; ++nt) {
                pi = fmaf(acc[mt][nt][r], aiv[nt], pi);
                pj = fmaf(acc[mt][nt][r], ajv[nt], pj);
            }
#pragma unroll
            for (int off = 8; off > 0; off >>= 1) {
                pi += __shfl_down(pi, off, 16);
                pj += __shfl_down(pj, off, 16);
            }
            if (col == 0) {
                const int n = nb + mt * 16 + quad * 4 + r;
                s_i[n * HEADS + w] = pi;
                s_j[n * HEADS + w] = pj;
            }
        }
    }
    __syncthreads();   // xh/xl consumed; smem becomes the transpose buffer

    // stage transposed bf16 tile: lt[node][o*4+head] with padded row stride
    short* lt = (short*)smemv;
#pragma unroll
    for (int mt = 0; mt < 2; ++mt)
#pragma unroll
        for (int nt = 0; nt < 4; ++nt)
#pragma unroll
            for (int r = 0; r < 4; ++r)
                lt[(mt * 16 + quad * 4 + r) * LTROW + (nt * 16 + col) * 4 + w] =
                    (short)f2bf(acc[mt][nt][r]);
    __syncthreads();

    // dense write-out: 2048 uint2 = 16 KB, coalesced 8B stores
    uint2* hg = (uint2*)(h2 + (size_t)nb * (DIM_OUT * HEADS));
#pragma unroll
    for (int r = 0; r < 8; ++r) {
        const int idx = t + 256 * r;       // 0..2047
        const int node = idx >> 6;
        const int wo = idx & 63;
        hg[idx] = *(const uint2*)(lt + node * LTROW + wo * 4);
    }
}

// ---------------- D2: csr blocks [0,128) ∥ MFMA-gemm blocks [128,1691) ------------
// csr block r: walk the 128 chunk-runs of range r via offT; single writer of its
// sdst lines; emits cursor degrees. gemm co-dispatched (independent of sort chain).
__global__ __launch_bounds__(256) void csr_gemm_kernel(
    const float* __restrict__ x, const unsigned short* __restrict__ Wph,
    const unsigned short* __restrict__ Wpl, const float* __restrict__ a,
    unsigned short* __restrict__ h2, float* __restrict__ s_i, float* __restrict__ s_j,
    const unsigned int* __restrict__ offT, const unsigned int* __restrict__ ebuf,
    unsigned short* __restrict__ sdst, int* __restrict__ cursor)
{
    __shared__ __align__(16) unsigned char smem[SMEM_BYTES];  // 17408 B, dual-use
    const int b = blockIdx.x;
    const int t = threadIdx.x;

    if (b < RANGES) {
        unsigned int* cur  = (unsigned int*)smem;      // [RSPAN]
        unsigned int* offA = cur + RSPAN;              // [CHUNKS]
        unsigned int* offB = offA + CHUNKS;            // [CHUNKS]
        const int r = b;
        for (int i = t; i < RSPAN; i += 256) cur[i] = 0u;
        if (t < CHUNKS) {
            offA[t] = offT[t * OPITCH + r];
            offB[t] = offT[t * OPITCH + r + 1];
        }
        __syncthreads();
        const int w = t >> 6, lane = t & 63;
        for (int c = w; c < CHUNKS; c += 4) {
            const unsigned int j0 = offA[c], j1 = offB[c];
            for (unsigned int e = j0 + lane; e < j1; e += 64) {
                const unsigned int v = ebuf[e];
                const unsigned int sl = v >> 16;
                const unsigned int d = v & 0xFFFFu;
                const unsigned int slot = atomicAdd(&cur[sl], 1u);
                if (slot < PAD) sdst[(size_t)(r * RSPAN + sl) * PAD + slot] = (unsigned short)d;
            }
        }
        __syncthreads();
        for (int i = t; i < RSPAN; i += 256) {
            const int n = r * RSPAN + i;
            if (n < N_NODES) cursor[n] = (int)cur[i];
        }
        return;
    }

    gemm_role((b - RANGES) * NPB, t, x, Wph, Wpl, a, h2, s_i, s_j, smem);
}

// ---------------- D3: fused per-src softmax + aggregate (proven 62.6 us body) -----
__global__ __launch_bounds__(256) void fused_kernel(
    const int* __restrict__ cursor, const unsigned short* __restrict__ sdst,
    const float* __restrict__ s_i, const float* __restrict__ s_j,
    const unsigned short* __restrict__ h2, float* __restrict__ out)
{
    __shared__ float4 att_s[4][64];
    __shared__ int    dst_s[4][64];
    const int w = (threadIdx.x >> 6) & 3;
    const int lane = threadIdx.x & 63;
    const int n = blockIdx.x * 4 + w;
    if (n >= N_NODES) return;
    const int d = min(cursor[n], PAD);
    const int start = n * PAD;

    float acc = 0.f;
    if (d > 0) {
        const float4 si = *(const float4*)(s_i + n * HEADS);
        float4 m4 = {-INFINITY, -INFINITY, -INFINITY, -INFINITY};
        float4 cz = {-INFINITY, -INFINITY, -INFINITY, -INFINITY};
        int cdst = 0;
        if (lane < d) {
            cdst = (int)sdst[start + lane];
            const float4 sj = *(const float4*)(s_j + cdst * HEADS);
            float z0 = si.x + sj.x, z1 = si.y + sj.y, z2 = si.z + sj.z, z3 = si.w + sj.w;
            cz.x = z0 >= 0.f ? z0 : NEG_SLOPE * z0;
            cz.y = z1 >= 0.f ? z1 : NEG_SLOPE * z1;
            cz.z = z2 >= 0.f ? z2 : NEG_SLOPE * z2;
            cz.w = z3 >= 0.f ? z3 : NEG_SLOPE * z3;
            m4 = cz;
        }
#pragma unroll
        for (int off = 32; off > 0; off >>= 1) {
            m4.x = fmaxf(m4.x, __shfl_xor(m4.x, off, 64));
            m4.y = fmaxf(m4.y, __shfl_xor(m4.y, off, 64));
            m4.z = fmaxf(m4.z, __shfl_xor(m4.z, off, 64));
            m4.w = fmaxf(m4.w, __shfl_xor(m4.w, off, 64));
        }
        float4 ex = {0.f, 0.f, 0.f, 0.f};
        if (lane < d) {
            ex.x = __expf(cz.x - m4.x);
            ex.y = __expf(cz.y - m4.y);
            ex.z = __expf(cz.z - m4.z);
            ex.w = __expf(cz.w - m4.w);
        }
        float4 sm = ex;
#pragma unroll
        for (int off = 32; off > 0; off >>= 1) {
            sm.x += __shfl_xor(sm.x, off, 64);
            sm.y += __shfl_xor(sm.y, off, 64);
            sm.z += __shfl_xor(sm.z, off, 64);
            sm.w += __shfl_xor(sm.w, off, 64);
        }
        if (lane < d) {
            att_s[w][lane] = make_float4(ex.x / sm.x, ex.y / sm.y, ex.z / sm.z, ex.w / sm.w);
            dst_s[w][lane] = cdst;
        }

        const unsigned short* hbase = h2 + lane * HEADS;
        int e = 0;
        for (; e + 8 <= d; e += 8) {
            uint2 hv[8];
            float4 at[8];
#pragma unroll
            for (int q = 0; q < 8; ++q) {
                const int dd = dst_s[w][e + q];
                at[q] = att_s[w][e + q];
                hv[q] = *(const uint2*)(hbase + (size_t)dd * (DIM_OUT * HEADS));
            }
#pragma unroll
            for (int q = 0; q < 8; ++q) {
                acc += at[q].x * bf2f(hv[q].x & 0xFFFFu) + at[q].y * bf2f(hv[q].x >> 16)
                     + at[q].z * bf2f(hv[q].y & 0xFFFFu) + at[q].w * bf2f(hv[q].y >> 16);
            }
        }
        for (; e + 4 <= d; e += 4) {
            uint2 hv[4];
            float4 at[4];
#pragma unroll
            for (int q = 0; q < 4; ++q) {
                const int dd = dst_s[w][e + q];
                at[q] = att_s[w][e + q];
                hv[q] = *(const uint2*)(hbase + (size_t)dd * (DIM_OUT * HEADS));
            }
#pragma unroll
            for (int q = 0; q < 4; ++q) {
                acc += at[q].x * bf2f(hv[q].x & 0xFFFFu) + at[q].y * bf2f(hv[q].x >> 16)
                     + at[q].z * bf2f(hv[q].y & 0xFFFFu) + at[q].w * bf2f(hv[q].y >> 16);
            }
        }
        for (; e < d; ++e) {
            const int dd = dst_s[w][e];
            const float4 a4 = att_s[w][e];
            const uint2 hv = *(const uint2*)(hbase + (size_t)dd * (DIM_OUT * HEADS));
            acc += a4.x * bf2f(hv.x & 0xFFFFu) + a4.y * bf2f(hv.x >> 16)
                 + a4.z * bf2f(hv.y & 0xFFFFu) + a4.w * bf2f(hv.y >> 16);
        }
    }
    out[n * DIM_OUT + lane] = 0.25f * acc;
}

extern "C" void kernel_launch(void* const* d_in, const int* in_sizes, int n_in,
                              void* d_out, int out_size, void* d_ws, size_t ws_size,
                              hipStream_t stream) {
    const float* x  = (const float*)d_in[0];
    const int*   ei = (const int*)d_in[1];
    const float* W  = (const float*)d_in[2];
    const float* a  = (const float*)d_in[3];
    float* out = (float*)d_out;

    char* ws = (char*)d_ws;
    size_t off = 0;
    auto alloc = [&](size_t bytes) { void* p = ws + off; off = (off + bytes + 511) & ~size_t(511); return p; };
    unsigned short* h2  = (unsigned short*)alloc(sizeof(unsigned short) * N_PAD * DIM_OUT * HEADS); // 25.6 MB
    float* s_i    = (float*)alloc(sizeof(float) * N_PAD * HEADS);
    float* s_j    = (float*)alloc(sizeof(float) * N_PAD * HEADS);
    int*   cursor = (int*)alloc(sizeof(int) * N_NODES);                         // 200 KB
    unsigned short* sdst = (unsigned short*)alloc(sizeof(unsigned short) * N_NODES * PAD); // 6.4 MB
    unsigned int* offT   = (unsigned int*)alloc(sizeof(unsigned int) * CHUNKS * OPITCH);   // 67.6 KB
    unsigned int* ebuf   = (unsigned int*)alloc(sizeof(unsigned int) * N_EDGES);// 3.2 MB
    unsigned short* Wph  = (unsigned short*)alloc(sizeof(unsigned short) * HEADS * DIM_IN * DIM_OUT); // 64 KB
    unsigned short* Wpl  = (unsigned short*)alloc(sizeof(unsigned short) * HEADS * DIM_IN * DIM_OUT); // 64 KB

    // D1: pack W (8 blocks) + per-chunk local range-sort (128 blocks)
    sort_kernel<<<8 + CHUNKS, 512, 0, stream>>>(W, Wph, Wpl, ei, offT, ebuf);

    // D2: single-writer CSR build (128 blocks) + MFMA gemm (1563 blocks)
    csr_gemm_kernel<<<RANGES + GEMM_BLOCKS, 256, 0, stream>>>(
        x, Wph, Wpl, a, h2, s_i, s_j, offT, ebuf, sdst, cursor);

    // D3: fused softmax + aggregate: one wave per node
    const int fb = (N_NODES + 3) / 4;
    fused_kernel<<<fb, 256, 0, stream>>>(cursor, sdst, s_i, s_j, h2, out);
}

// Round 7
// 167.672 us; speedup vs baseline: 7.0158x; 1.0129x over previous
//
#include <hip/hip_runtime.h>
#include <hip/hip_bf16.h>

#define N_NODES 50000
#define N_EDGES 800000
#define DIM_IN  128
#define DIM_OUT 64
#define HEADS   4
#define NEG_SLOPE 0.2f
#define NPB 32                                    // nodes per gemm block
#define GEMM_BLOCKS ((N_NODES + NPB - 1) / NPB)   // 1563
#define N_PAD (GEMM_BLOCKS * NPB)                 // 50016
#define PAD 64                                    // sdst row: [0]=deg, [1..63]=dsts
#define MAXD 63                                   // max stored dsts per node
#define CHUNKS 128                                // edge chunks
#define EPC (N_EDGES / CHUNKS)                    // 6250 edges per chunk
#define RANGES 128                                // src ranges (single-writer CSR build)
#define RSPAN 391                                 // 128*391 = 50048 >= N_NODES
#define OPITCH 132                                // offT row pitch (129 used, padded)
#define XROW 136                                  // LDS row stride (shorts) for x hi/lo
#define LTROW 260                                 // LDS row stride (shorts) for transpose buffer
#define SMEM_BYTES (2 * NPB * XROW * 2)           // 17408

typedef __attribute__((ext_vector_type(8))) short short8;
typedef __attribute__((ext_vector_type(4))) short short4v;
typedef __attribute__((ext_vector_type(4))) float f32x4;

// bf16 helpers (RNE pack, exact shift unpack)
__device__ __forceinline__ unsigned int f2bf(float f) {
    unsigned int u = __float_as_uint(f);
    return (u + 0x7FFFu + ((u >> 16) & 1u)) >> 16;
}
__device__ __forceinline__ float bf2f(unsigned int b) {
    return __uint_as_float(b << 16);
}

// ---- pack W into MFMA B-frag hi/lo; i = fragment-lane 0..4095
__device__ __forceinline__ void packW_role(
    int i, const float* __restrict__ W,
    unsigned short* __restrict__ Wph, unsigned short* __restrict__ Wpl)
{
    const int lane = i & 63, nt = (i >> 6) & 3, kc = (i >> 8) & 3, h = (i >> 10) & 3;
    const int col = lane & 15, quad = lane >> 4;
    unsigned short hv[8], lv[8];
#pragma unroll
    for (int j = 0; j < 8; ++j) {
        const int k = kc * 32 + quad * 8 + j;
        const int n = nt * 16 + col;
        const float f = W[h * (DIM_IN * DIM_OUT) + k * DIM_OUT + n];
        const unsigned int hb = f2bf(f);
        hv[j] = (unsigned short)hb;
        lv[j] = (unsigned short)f2bf(f - bf2f(hb));
    }
    *(short8*)(Wph + (size_t)i * 8) = *(short8*)hv;
    *(short8*)(Wpl + (size_t)i * 8) = *(short8*)lv;
}

// ---------------- D1: pack W (blocks 0-7) + per-chunk local range-sort (8..135) ---
__global__ __launch_bounds__(512) void sort_kernel(
    const float* __restrict__ W, unsigned short* __restrict__ Wph,
    unsigned short* __restrict__ Wpl, const int* __restrict__ ei,
    unsigned int* __restrict__ offT, unsigned int* __restrict__ ebuf)
{
    const int b = blockIdx.x;
    const int t = threadIdx.x;
    if (b < 8) { packW_role(b * 512 + t, W, Wph, Wpl); return; }

    __shared__ unsigned int hist[RANGES];
    __shared__ unsigned int scn[RANGES + 1];
    __shared__ unsigned int cur[RANGES];
    const int c = b - 8;
    if (t < RANGES) hist[t] = 0u;
    __syncthreads();
    const int* srcp = ei + c * EPC;
    const int* dstp = ei + N_EDGES + c * EPC;
    for (int e = t; e < EPC; e += 512) atomicAdd(&hist[srcp[e] / RSPAN], 1u);
    __syncthreads();
    // Hillis-Steele scan (threads 0..127), exclusive via scn[t+1]=hist[t]
    if (t < RANGES) scn[t + 1] = hist[t];
    if (t == 0) scn[0] = 0u;
    __syncthreads();
    for (int off = 1; off < RANGES; off <<= 1) {
        unsigned int v = 0u;
        if (t < RANGES && (t + 1) > off) v = scn[t + 1 - off];
        __syncthreads();
        if (t < RANGES) scn[t + 1] += v;
        __syncthreads();
    }
    if (t < RANGES) {
        cur[t] = scn[t];
        offT[c * OPITCH + t] = (unsigned int)(c * EPC) + scn[t];
    }
    if (t == 0) offT[c * OPITCH + RANGES] = (unsigned int)((c + 1) * EPC);
    __syncthreads();
    unsigned int* eb = ebuf + (size_t)c * EPC;
    for (int e = t; e < EPC; e += 512) {
        const int s = srcp[e];
        const int d = dstp[e];
        const int r = s / RSPAN;
        const unsigned int pos = atomicAdd(&cur[r], 1u);
        eb[pos] = ((unsigned int)(s - r * RSPAN) << 16) | (unsigned int)d;
    }
}

// ---- MFMA gemm tile for nodes [nb, nb+32) (256 threads, smem = 17408 B)
__device__ __forceinline__ void gemm_role(
    int nb, int t, const float* __restrict__ x,
    const unsigned short* __restrict__ Wph, const unsigned short* __restrict__ Wpl,
    const float* __restrict__ a, unsigned short* __restrict__ h2,
    float* __restrict__ s_i, float* __restrict__ s_j, void* smemv)
{
    short* xh = (short*)smemv;            // [NPB][XROW]
    short* xl = xh + NPB * XROW;

    // stage x tile as hi/lo bf16 (32 nodes x 128 dims)
    {
        const float4* xg = (const float4*)x;
        const int base = nb * (DIM_IN / 4);
        const int limit = N_NODES * (DIM_IN / 4);
#pragma unroll
        for (int r = 0; r < 4; ++r) {
            const int idx = t + 256 * r;              // 0..1023
            const int gi = base + idx;
            float4 v = {0.f, 0.f, 0.f, 0.f};
            if (gi < limit) v = xg[gi];
            const int node = idx >> 5;
            const int dg = (idx & 31) * 4;
            unsigned short hs[4], ls[4];
            const float fv[4] = {v.x, v.y, v.z, v.w};
#pragma unroll
            for (int c = 0; c < 4; ++c) {
                const unsigned int hb = f2bf(fv[c]);
                hs[c] = (unsigned short)hb;
                ls[c] = (unsigned short)f2bf(fv[c] - bf2f(hb));
            }
            *(short4v*)(xh + node * XROW + dg) = *(short4v*)hs;
            *(short4v*)(xl + node * XROW + dg) = *(short4v*)ls;
        }
    }
    __syncthreads();

    const int w = t >> 6;        // wave id == head
    const int lane = t & 63;
    const int col = lane & 15, quad = lane >> 4;

    f32x4 acc[2][4];
#pragma unroll
    for (int mt = 0; mt < 2; ++mt)
#pragma unroll
        for (int nt = 0; nt < 4; ++nt) acc[mt][nt] = (f32x4){0.f, 0.f, 0.f, 0.f};

    const short8* Bh = (const short8*)Wph;
    const short8* Bl = (const short8*)Wpl;
#pragma unroll
    for (int kc = 0; kc < 4; ++kc) {
        const short8 ah0 = *(const short8*)(xh + (0 * 16 + col) * XROW + kc * 32 + quad * 8);
        const short8 al0 = *(const short8*)(xl + (0 * 16 + col) * XROW + kc * 32 + quad * 8);
        const short8 ah1 = *(const short8*)(xh + (1 * 16 + col) * XROW + kc * 32 + quad * 8);
        const short8 al1 = *(const short8*)(xl + (1 * 16 + col) * XROW + kc * 32 + quad * 8);
#pragma unroll
        for (int nt = 0; nt < 4; ++nt) {
            const int fi = ((w * 4 + kc) * 4 + nt) * 64 + lane;
            const short8 bh = Bh[fi];
            const short8 bl = Bl[fi];
            acc[0][nt] = __builtin_amdgcn_mfma_f32_16x16x32_bf16(ah0, bh, acc[0][nt], 0, 0, 0);
            acc[0][nt] = __builtin_amdgcn_mfma_f32_16x16x32_bf16(al0, bh, acc[0][nt], 0, 0, 0);
            acc[0][nt] = __builtin_amdgcn_mfma_f32_16x16x32_bf16(ah0, bl, acc[0][nt], 0, 0, 0);
            acc[1][nt] = __builtin_amdgcn_mfma_f32_16x16x32_bf16(ah1, bh, acc[1][nt], 0, 0, 0);
            acc[1][nt] = __builtin_amdgcn_mfma_f32_16x16x32_bf16(al1, bh, acc[1][nt], 0, 0, 0);
            acc[1][nt] = __builtin_amdgcn_mfma_f32_16x16x32_bf16(ah1, bl, acc[1][nt], 0, 0, 0);
        }
    }

    // scores: lane holds h[node=mt*16+quad*4+r][head=w][o=nt*16+col]
    float aiv[4], ajv[4];
#pragma unroll
    for (int nt = 0; nt < 4; ++nt) {
        aiv[nt] = a[w * (2 * DIM_OUT) + nt * 16 + col];
        ajv[nt] = a[w * (2 * DIM_OUT) + DIM_OUT + nt * 16 + col];
    }
#pragma unroll
    for (int mt = 0; mt < 2; ++mt) {
#pragma unroll
        for (int r = 0; r < 4; ++r) {
            float pi = 0.f, pj = 0.f;
#pragma unroll
            for (int nt = 0; nt < 4; ++nt) {
                pi = fmaf(acc[mt][nt][r], aiv[nt], pi);
                pj = fmaf(acc[mt][nt][r], ajv[nt], pj);
            }
#pragma unroll
            for (int off = 8; off > 0; off >>= 1) {
                pi += __shfl_down(pi, off, 16);
                pj += __shfl_down(pj, off, 16);
            }
            if (col == 0) {
                const int n = nb + mt * 16 + quad * 4 + r;
                s_i[n * HEADS + w] = pi;
                s_j[n * HEADS + w] = pj;
            }
        }
    }
    __syncthreads();   // xh/xl consumed; smem becomes the transpose buffer

    // stage transposed bf16 tile: lt[node][o*4+head] with padded row stride
    short* lt = (short*)smemv;
#pragma unroll
    for (int mt = 0; mt < 2; ++mt)
#pragma unroll
        for (int nt = 0; nt < 4; ++nt)
#pragma unroll
            for (int r = 0; r < 4; ++r)
                lt[(mt * 16 + quad * 4 + r) * LTROW + (nt * 16 + col) * 4 + w] =
                    (short)f2bf(acc[mt][nt][r]);
    __syncthreads();

    // dense write-out: 2048 uint2 = 16 KB, coalesced 8B stores
    uint2* hg = (uint2*)(h2 + (size_t)nb * (DIM_OUT * HEADS));
#pragma unroll
    for (int r = 0; r < 8; ++r) {
        const int idx = t + 256 * r;       // 0..2047
        const int node = idx >> 6;
        const int wo = idx & 63;
        hg[idx] = *(const uint2*)(lt + node * LTROW + wo * 4);
    }
}

// ---------------- D2: csr blocks [0,128) ∥ MFMA-gemm blocks [128,1691) ------------
// csr block r: single writer of range r's sdst rows. Row layout: [0]=deg (<=63),
// [1..deg]=dsts. No separate cursor array (degree header removes fused's 1st hop).
__global__ __launch_bounds__(256) void csr_gemm_kernel(
    const float* __restrict__ x, const unsigned short* __restrict__ Wph,
    const unsigned short* __restrict__ Wpl, const float* __restrict__ a,
    unsigned short* __restrict__ h2, float* __restrict__ s_i, float* __restrict__ s_j,
    const unsigned int* __restrict__ offT, const unsigned int* __restrict__ ebuf,
    unsigned short* __restrict__ sdst)
{
    __shared__ __align__(16) unsigned char smem[SMEM_BYTES];  // 17408 B, dual-use
    const int b = blockIdx.x;
    const int t = threadIdx.x;

    if (b < RANGES) {
        unsigned int* cur  = (unsigned int*)smem;      // [RSPAN]
        unsigned int* offA = cur + RSPAN;              // [CHUNKS]
        unsigned int* offB = offA + CHUNKS;            // [CHUNKS]
        const int r = b;
        for (int i = t; i < RSPAN; i += 256) cur[i] = 0u;
        if (t < CHUNKS) {
            offA[t] = offT[t * OPITCH + r];
            offB[t] = offT[t * OPITCH + r + 1];
        }
        __syncthreads();
        const int w = t >> 6, lane = t & 63;
        for (int c = w; c < CHUNKS; c += 4) {
            const unsigned int j0 = offA[c], j1 = offB[c];
            for (unsigned int e = j0 + lane; e < j1; e += 64) {
                const unsigned int v = ebuf[e];
                const unsigned int sl = v >> 16;
                const unsigned int d = v & 0xFFFFu;
                const unsigned int slot = atomicAdd(&cur[sl], 1u);
                if (slot < MAXD) sdst[(size_t)(r * RSPAN + sl) * PAD + 1 + slot] = (unsigned short)d;
            }
        }
        __syncthreads();
        for (int i = t; i < RSPAN; i += 256) {
            const int n = r * RSPAN + i;
            if (n < N_NODES) sdst[(size_t)n * PAD] = (unsigned short)min(cur[i], (unsigned int)MAXD);
        }
        return;
    }

    gemm_role((b - RANGES) * NPB, t, x, Wph, Wpl, a, h2, s_i, s_j, smem);
}

// ---------------- D3: fused softmax + aggregate (latency-chain-shortened) ---------
// Chain: sdst row (deg inline) -> {issue h2 batch-0 || s_j load || softmax} ->
// consume batch-0 free, later batches load+consume. Zero-padded att kills tails.
__global__ __launch_bounds__(256) void fused_kernel(
    const unsigned short* __restrict__ sdst,
    const float* __restrict__ s_i, const float* __restrict__ s_j,
    const unsigned short* __restrict__ h2, float* __restrict__ out)
{
    __shared__ float4 att_s[4][64];
    __shared__ int    dst_s[4][64];
    const int w = (threadIdx.x >> 6) & 3;
    const int lane = threadIdx.x & 63;
    const int n = blockIdx.x * 4 + w;
    if (n >= N_NODES) return;

    // one coalesced row read: lane0 = degree, lanes 1..d = dst indices
    const int myv = (int)sdst[(size_t)n * PAD + lane];
    const int d = __shfl(myv, 0, 64);

    if (d == 0) { out[n * DIM_OUT + lane] = 0.f; return; }

    // zero-init tables, then place this wave's entries (within-wave LDS ordering)
    att_s[w][lane] = make_float4(0.f, 0.f, 0.f, 0.f);
    dst_s[w][lane] = 0;
    const bool has_edge = (lane >= 1) && (lane <= d);
    if (has_edge) dst_s[w][lane - 1] = myv;

    // issue gather batch-0 NOW (hides under s_j load + softmax below)
    const unsigned short* hbase = h2 + lane * HEADS;
    uint2 hv[8];
#pragma unroll
    for (int q = 0; q < 8; ++q)
        hv[q] = *(const uint2*)(hbase + (size_t)dst_s[w][q] * (DIM_OUT * HEADS));

    // softmax phase
    const float4 si = *(const float4*)(s_i + n * HEADS);
    float4 m4 = {-INFINITY, -INFINITY, -INFINITY, -INFINITY};
    float4 cz = {-INFINITY, -INFINITY, -INFINITY, -INFINITY};
    if (has_edge) {
        const float4 sj = *(const float4*)(s_j + myv * HEADS);
        float z0 = si.x + sj.x, z1 = si.y + sj.y, z2 = si.z + sj.z, z3 = si.w + sj.w;
        cz.x = z0 >= 0.f ? z0 : NEG_SLOPE * z0;
        cz.y = z1 >= 0.f ? z1 : NEG_SLOPE * z1;
        cz.z = z2 >= 0.f ? z2 : NEG_SLOPE * z2;
        cz.w = z3 >= 0.f ? z3 : NEG_SLOPE * z3;
        m4 = cz;
    }
#pragma unroll
    for (int off = 32; off > 0; off >>= 1) {
        m4.x = fmaxf(m4.x, __shfl_xor(m4.x, off, 64));
        m4.y = fmaxf(m4.y, __shfl_xor(m4.y, off, 64));
        m4.z = fmaxf(m4.z, __shfl_xor(m4.z, off, 64));
        m4.w = fmaxf(m4.w, __shfl_xor(m4.w, off, 64));
    }
    float4 ex = {0.f, 0.f, 0.f, 0.f};
    if (has_edge) {
        ex.x = __expf(cz.x - m4.x);
        ex.y = __expf(cz.y - m4.y);
        ex.z = __expf(cz.z - m4.z);
        ex.w = __expf(cz.w - m4.w);
    }
    float4 sm = ex;
#pragma unroll
    for (int off = 32; off > 0; off >>= 1) {
        sm.x += __shfl_xor(sm.x, off, 64);
        sm.y += __shfl_xor(sm.y, off, 64);
        sm.z += __shfl_xor(sm.z, off, 64);
        sm.w += __shfl_xor(sm.w, off, 64);
    }
    if (has_edge) att_s[w][lane - 1] = ex;     // raw ex; normalize once at the end

    float a0 = 0.f, a1 = 0.f, a2 = 0.f, a3 = 0.f;
    const int nb8 = (d + 7) >> 3;
    int bb = 0;
    while (true) {
#pragma unroll
        for (int q = 0; q < 8; ++q) {
            const float4 at = att_s[w][bb * 8 + q];
            const uint2 v = hv[q];
            a0 = fmaf(at.x, __uint_as_float(v.x << 16), a0);
            a1 = fmaf(at.y, __uint_as_float(v.x & 0xFFFF0000u), a1);
            a2 = fmaf(at.z, __uint_as_float(v.y << 16), a2);
            a3 = fmaf(at.w, __uint_as_float(v.y & 0xFFFF0000u), a3);
        }
        if (++bb >= nb8) break;
#pragma unroll
        for (int q = 0; q < 8; ++q)
            hv[q] = *(const uint2*)(hbase + (size_t)dst_s[w][bb * 8 + q] * (DIM_OUT * HEADS));
    }

    out[n * DIM_OUT + lane] = 0.25f * (a0 / sm.x + a1 / sm.y + a2 / sm.z + a3 / sm.w);
}

extern "C" void kernel_launch(void* const* d_in, const int* in_sizes, int n_in,
                              void* d_out, int out_size, void* d_ws, size_t ws_size,
                              hipStream_t stream) {
    const float* x  = (const float*)d_in[0];
    const int*   ei = (const int*)d_in[1];
    const float* W  = (const float*)d_in[2];
    const float* a  = (const float*)d_in[3];
    float* out = (float*)d_out;

    char* ws = (char*)d_ws;
    size_t off = 0;
    auto alloc = [&](size_t bytes) { void* p = ws + off; off = (off + bytes + 511) & ~size_t(511); return p; };
    unsigned short* h2  = (unsigned short*)alloc(sizeof(unsigned short) * N_PAD * DIM_OUT * HEADS); // 25.6 MB
    float* s_i    = (float*)alloc(sizeof(float) * N_PAD * HEADS);
    float* s_j    = (float*)alloc(sizeof(float) * N_PAD * HEADS);
    unsigned short* sdst = (unsigned short*)alloc(sizeof(unsigned short) * N_NODES * PAD); // 6.4 MB
    unsigned int* offT   = (unsigned int*)alloc(sizeof(unsigned int) * CHUNKS * OPITCH);   // 67.6 KB
    unsigned int* ebuf   = (unsigned int*)alloc(sizeof(unsigned int) * N_EDGES);// 3.2 MB
    unsigned short* Wph  = (unsigned short*)alloc(sizeof(unsigned short) * HEADS * DIM_IN * DIM_OUT); // 64 KB
    unsigned short* Wpl  = (unsigned short*)alloc(sizeof(unsigned short) * HEADS * DIM_IN * DIM_OUT); // 64 KB

    // D1: pack W (8 blocks) + per-chunk local range-sort (128 blocks)
    sort_kernel<<<8 + CHUNKS, 512, 0, stream>>>(W, Wph, Wpl, ei, offT, ebuf);

    // D2: single-writer CSR build (128 blocks) + MFMA gemm (1563 blocks)
    csr_gemm_kernel<<<RANGES + GEMM_BLOCKS, 256, 0, stream>>>(
        x, Wph, Wpl, a, h2, s_i, s_j, offT, ebuf, sdst);

    // D3: fused softmax + aggregate: one wave per node
    const int fb = (N_NODES + 3) / 4;
    fused_kernel<<<fb, 256, 0, stream>>>(sdst, s_i, s_j, h2, out);
}